// Round 15
// baseline (812.997 us; speedup 1.0000x reference)
//
#include <hip/hip_runtime.h>
#include <stdint.h>

// ===== LinearQ4_0: out[8192,11008] = x[8192,4096] * W^T, W q4_0 packed =====
#define IN_F   4096
#define OUT_F  11008
#define M_ROWS 8192
#define BM 256
#define BN 256
#define BK 64
#define NTILE_K (IN_F / BK)   // 64 K-tiles (= 64 scale groups), 2 per iteration

typedef __attribute__((ext_vector_type(4))) float  f32x4;
typedef __attribute__((ext_vector_type(4))) int    int4v;
typedef __attribute__((ext_vector_type(4))) unsigned int uint4v;
typedef __attribute__((ext_vector_type(8))) unsigned short ushort8;
typedef _Float16 f16x8 __attribute__((ext_vector_type(8)));
typedef _Float16 f16x2 __attribute__((ext_vector_type(2)));

// ---- kernel 1: repack q4_0 -> INTERLEAVED biased nibbles wq[OUT_F][IN_F/8] u32 ----
// u32 c of row o: elem e (k = 8c+e) -> nibble pos (e>>1) + (e&1)*4, value q+8.
__global__ __launch_bounds__(256) void pack_w(const int* __restrict__ w,
                                              unsigned int* __restrict__ wq) {
  const int totald = OUT_F * (IN_F / 8);
  for (int d = blockIdx.x * blockDim.x + threadIdx.x; d < totald;
       d += gridDim.x * blockDim.x) {
    const int o   = d >> 9;
    const int k0  = (d & 511) * 8;
    const int n   = o * 64 + (k0 >> 6);
    const int p   = n >> 1;
    const int nib = n & 1;
    const int j0  = k0 & 63;
    const int* src = w + p * 64 + j0;
    const int4v b0 = __builtin_nontemporal_load(reinterpret_cast<const int4v*>(src));
    const int4v b1 = __builtin_nontemporal_load(reinterpret_cast<const int4v*>(src + 4));
    unsigned int acc = 0;
#pragma unroll
    for (int i = 0; i < 8; ++i) {
      const int b = (i < 4) ? b0[i] : b1[i - 4];
      const int q = nib ? ((b << 28) >> 28) : (b >> 4);
      const int pos = (i >> 1) + ((i & 1) << 2);
      acc |= ((unsigned int)((q + 8) & 0xF)) << (4 * pos);
    }
    wq[d] = acc;
  }
}

// ---- kernel 1b: transpose scales fp32 s[OUT_F][64] -> fp16 st[64][OUT_F] ----
__global__ __launch_bounds__(256) void scale_t(const float* __restrict__ s,
                                               unsigned short* __restrict__ st) {
  const int o = blockIdx.x * 256 + threadIdx.x;
  const int g = blockIdx.y;
  if (o < OUT_F) {
    _Float16 h = (_Float16)s[o * 64 + g];
    st[g * OUT_F + o] = __builtin_bit_cast(unsigned short, h);
  }
}

// ---- kernel 2: x fp32 -> fp16 (exact round-trip; input was fp16) ----
__global__ __launch_bounds__(256) void cvt_x(const float* __restrict__ x,
                                             unsigned short* __restrict__ xb) {
  const int total8 = (M_ROWS * IN_F) / 8;
  for (int t = blockIdx.x * blockDim.x + threadIdx.x; t < total8;
       t += gridDim.x * blockDim.x) {
    const f32x4 a0 = __builtin_nontemporal_load(reinterpret_cast<const f32x4*>(x + t * 8));
    const f32x4 a1 = __builtin_nontemporal_load(reinterpret_cast<const f32x4*>(x + t * 8 + 4));
    ushort8 r;
#pragma unroll
    for (int e = 0; e < 4; ++e) {
      r[e]     = __builtin_bit_cast(unsigned short, (_Float16)a0[e]);
      r[4 + e] = __builtin_bit_cast(unsigned short, (_Float16)a1[e]);
    }
    *reinterpret_cast<ushort8*>(xb + t * 8) = r;
  }
}

// ---- async global -> LDS, 16 B per lane ----
__device__ __forceinline__ void gld16(const void* g, void* l) {
  __builtin_amdgcn_global_load_lds(
      (const __attribute__((address_space(1))) unsigned int*)(uintptr_t)g,
      (__attribute__((address_space(3))) unsigned int*)(unsigned int)(uintptr_t)l,
      16, 0, 0);
}

#define BAR() do { asm volatile("" ::: "memory"); __builtin_amdgcn_s_barrier(); \
                   asm volatile("" ::: "memory"); } while (0)
#define SCHEDB() __builtin_amdgcn_sched_barrier(0)

// ---- kernel 3: 8-phase, 1 bar/phase, POST-BARRIER dequant (VALU || MFMA). ----
// Phase-top: STAGE + RD_A(next) + RD_BQ raw/scale LDS loads (lgkm handled by
// compiler).  Post-BAR: sched_barrier pins {DEQ_C (pure VALU, next operands) ;
// MFMA(P)} below the barrier; they are independent -> scheduler interleaves,
// dequant hides in the MFMA pipe's shadow (m114: separate pipes co-issue).
// Loads/iter & waits IDENTICAL to R14 (ledger unchanged, FIFO-sim verified):
//   P1{A11 x2,BQ1} VW(5); P3{A00' x2} VW(2); P4{BQ0'}; P5{A01' x2}; P7{A10' x2} VW(4).
// LDS: A bufs ([kh][256][32] f16, chunk^=((row>>1)&3)); BQ bufs (XOR-swizzled
// phys4 = s^(((s>>5)&7)<<2)); SL scales [64][256] staged once. 112 KB.
// Dequant math (R13-proven exact): (0x6400|n)=1024+n; fma(v,s,-1024s)+(-8s)=q*s.
__global__ __launch_bounds__(512, 2) void gemm_bt(const unsigned short* __restrict__ A,
                                                  const unsigned char* __restrict__ WQ,
                                                  const unsigned short* __restrict__ ST,
                                                  float* __restrict__ C) {
  __shared__ __align__(16) unsigned short lds[57344];  // 112 KB

  const int NT  = OUT_F / BN;              // 43
  const int nwg = (M_ROWS / BM) * NT;      // 1376, %8==0
  const int cpx = nwg >> 3;
  const int bid = blockIdx.x;
  const int swz = (bid & 7) * cpx + (bid >> 3);
  const int mt  = swz / NT;
  const int nt  = swz - mt * NT;
  const int n0  = nt * BN;

  const int tid  = threadIdx.x;
  const int lane = tid & 63;
  const int wid  = tid >> 6;      // 8 waves: 2 (M) x 4 (N)
  const int wr   = wid >> 2;
  const int wc   = wid & 3;

  // ---- A staging ----
  const int r_st = tid >> 2;
  const int lc   = (tid & 3) ^ ((tid >> 3) & 3);
  const unsigned short* gA = A + (size_t)(mt * BM + r_st) * IN_F + lc * 8;
  unsigned short* ldsw = lds + tid * 8;

#define STAGE_A(b, h, kk) do {                                              \
    unsigned short* d_ = ldsw + (b) * 16384 + (h) * 8192;                   \
    const unsigned short* s_ = gA + (kk) + (h) * 32;                        \
    gld16(s_, d_); gld16(s_ + (size_t)128 * IN_F, d_ + 4096);               \
  } while (0)

  // ---- BQ staging: dest chunk16 = tid (linear); logical chunk = tid ^ ((tid>>3)&7) ----
  const int bql = tid ^ ((tid >> 3) & 7);
  const unsigned char* gBQ = WQ + (size_t)(n0 + (bql >> 1)) * (IN_F / 2) + (bql & 1) * 16;
#define STAGE_BQ(b, tk) \
    gld16(gBQ + (size_t)(tk) * 32, lds + 32768 + (b) * 4096 + tid * 8)

  // ---- SL staging (prologue only) ----
#define STAGE_SL(c) do {                                                    \
    const int sl_ = (c) * 512 + tid;                                        \
    gld16(ST + (size_t)(sl_ >> 5) * OUT_F + n0 + (sl_ & 31) * 8,            \
          lds + 40960 + sl_ * 8);                                           \
  } while (0)

  // ---- fragment reads ----
  const int fr   = lane & 15;
  const int kq   = lane >> 4;
  const int coff = (kq ^ ((fr >> 1) & 3)) * 8;

  f16x8 afrA[4], afrB[4], bfrA[4], bfrB[4];
  unsigned int rawB[4];
  _Float16     scB[4];

#define RD_A(dst, b, h, mq) do {                                            \
    const unsigned short* p_ = lds + (b) * 16384 + (h) * 8192 + coff;       \
    _Pragma("unroll") for (int mm = 0; mm < 4; ++mm)                        \
      dst[mm] = *reinterpret_cast<const f16x8*>(                            \
          p_ + (size_t)(wr * 128 + (mq) * 64 + mm * 16 + fr) * 32);         \
  } while (0)

  // phase-top: raw nibble u32 + scale loads (LDS); pure loads, no VALU math
#define RD_BQ(bbuf, kh, g) do {                                             \
    _Pragma("unroll") for (int nn = 0; nn < 4; ++nn) {                      \
      const int o_ = wc * 64 + nn * 16 + fr;                                \
      const int s4_ = o_ * 8 + (kh) * 4 + kq;                               \
      const int ph_ = s4_ ^ (((s4_ >> 5) & 7) << 2);                        \
      rawB[nn] = *reinterpret_cast<const unsigned int*>(                    \
          lds + 32768 + (bbuf) * 4096 + ph_ * 2);                           \
      scB[nn]  = *reinterpret_cast<const _Float16*>(                        \
          lds + 40960 + (g) * 256 + o_);                                    \
    }                                                                       \
  } while (0)

  // post-barrier: pure-VALU dequant into dst (overlaps MFMA pipe)
#define DEQ_C(dst) do {                                                     \
    _Pragma("unroll") for (int nn = 0; nn < 4; ++nn) {                      \
      const _Float16 s_  = scB[nn];                                         \
      const _Float16 c1_ = s_ * (_Float16)(-1024.0f);  /* exact */          \
      const _Float16 c8_ = s_ * (_Float16)(-8.0f);     /* exact */          \
      f16x2 s2; s2[0] = s_;  s2[1] = s_;                                    \
      f16x2 c1; c1[0] = c1_; c1[1] = c1_;                                   \
      f16x2 c8; c8[0] = c8_; c8[1] = c8_;                                   \
      uint4v rr;                                                            \
      _Pragma("unroll") for (int p = 0; p < 4; ++p) {                       \
        const unsigned int m_ = ((rawB[nn] >> (4 * p)) & 0x000F000Fu)       \
                              | 0x64006400u;                                \
        f16x2 v_ = __builtin_bit_cast(f16x2, m_);                           \
        v_ = __builtin_elementwise_fma(v_, s2, c1);                         \
        v_ = v_ + c8;                                                       \
        rr[p] = __builtin_bit_cast(unsigned int, v_);                       \
      }                                                                     \
      dst[nn] = __builtin_bit_cast(f16x8, rr);                              \
    }                                                                       \
  } while (0)

  f32x4 acc[8][4] = {};
#define MFMA16(mq, aset, bset) do {                                         \
    __builtin_amdgcn_s_setprio(1);                                          \
    _Pragma("unroll") for (int mm = 0; mm < 4; ++mm)                        \
      _Pragma("unroll") for (int nn = 0; nn < 4; ++nn)                      \
        acc[(mq)*4+mm][nn] = __builtin_amdgcn_mfma_f32_16x16x32_f16(        \
            aset[mm], bset[nn], acc[(mq)*4+mm][nn], 0, 0, 0);               \
    __builtin_amdgcn_s_setprio(0);                                          \
  } while (0)

#define VW(n) asm volatile("s_waitcnt vmcnt(" #n ")" ::: "memory")

  // ---- prologue: 11 loads; VW(4) drains SLx4+A00x2+BQ0; outstanding [A01x2,A10x2] ----
  STAGE_SL(0); STAGE_SL(1); STAGE_SL(2); STAGE_SL(3);
  STAGE_A(0, 0, 0);
  STAGE_BQ(0, 0);
  STAGE_A(0, 1, 0);
  STAGE_A(1, 0, BK);
  VW(4);
  BAR();
  RD_A(afrA, 0, 0, 0);
  RD_BQ(0, 0, 0); DEQ_C(bfrA);

  for (int it = 0; it < NTILE_K / 2; ++it) {
    const int ta  = 2 * it;
    const int tb  = 2 * it + 1;
    const int tna = (2 * it + 2) & (NTILE_K - 1);
    const int tnb = (2 * it + 3) & (NTILE_K - 1);

    // P1: stage A11(tb)+BQ1(tb) ; RD A(0,0,m4-7) ; VW(5) ; MFMA(afrA,bfrA)
    STAGE_A(1, 1, tb * BK); STAGE_BQ(1, tb);
    RD_A(afrB, 0, 0, 1);
    VW(5);
    BAR(); MFMA16(0, afrA, bfrA);
    // P2: RD A(0,1,m0-3) + raw B(0,kh1,ta) ; post-BAR {DEQ->bfrB || MFMA(afrB,bfrA)}
    RD_A(afrA, 0, 1, 0); RD_BQ(0, 1, ta);
    BAR(); SCHEDB();
    DEQ_C(bfrB);
    MFMA16(1, afrB, bfrA);
    // P3: stage A00'(tna) ; RD A(0,1,m4-7) ; VW(2) ; MFMA(afrA,bfrB)
    STAGE_A(0, 0, tna * BK);
    RD_A(afrB, 0, 1, 1);
    VW(2);
    BAR(); MFMA16(0, afrA, bfrB);
    // P4: stage BQ0'(tna) ; RD A(1,0,m0-3) + raw B(1,kh0,tb) ; {DEQ->bfrA || MFMA(afrB,bfrB)}
    STAGE_BQ(0, tna);
    RD_A(afrA, 1, 0, 0); RD_BQ(1, 0, tb);
    BAR(); SCHEDB();
    DEQ_C(bfrA);
    MFMA16(1, afrB, bfrB);
    // P5: stage A01'(tna) ; RD A(1,0,m4-7) ; MFMA(afrA,bfrA)
    STAGE_A(0, 1, tna * BK);
    RD_A(afrB, 1, 0, 1);
    BAR(); MFMA16(0, afrA, bfrA);
    // P6: RD A(1,1,m0-3) + raw B(1,kh1,tb) ; {DEQ->bfrB || MFMA(afrB,bfrA)}
    RD_A(afrA, 1, 1, 0); RD_BQ(1, 1, tb);
    BAR(); SCHEDB();
    DEQ_C(bfrB);
    MFMA16(1, afrB, bfrA);
    // P7: stage A10'(tnb) ; RD A(1,1,m4-7) ; VW(4) ; MFMA(afrA,bfrB)
    STAGE_A(1, 0, tnb * BK);
    RD_A(afrB, 1, 1, 1);
    VW(4);
    BAR(); MFMA16(0, afrA, bfrB);
    // P8: RD A(0,0,m0-3)' + raw B(0,kh0,tna)' ; {DEQ->bfrA || MFMA(afrB,bfrB)}
    RD_A(afrA, 0, 0, 0); RD_BQ(0, 0, tna);
    BAR(); SCHEDB();
    DEQ_C(bfrA);
    MFMA16(1, afrB, bfrB);
  }

  asm volatile("s_waitcnt vmcnt(0)" ::: "memory");  // drain tail stages

  // ---- epilogue: plain stores ----
  const int col  = n0 + wc * 64 + fr;
  const int row0 = mt * BM + wr * 128 + (lane >> 4) * 4;
#pragma unroll
  for (int m = 0; m < 8; ++m) {
#pragma unroll
    for (int n = 0; n < 4; ++n) {
      float* cp = C + (size_t)(row0 + m * 16) * OUT_F + (col + n * 16);
#pragma unroll
      for (int r = 0; r < 4; ++r) cp[(size_t)r * OUT_F] = acc[m][n][r];
    }
  }
}

extern "C" void kernel_launch(void* const* d_in, const int* in_sizes, int n_in,
                              void* d_out, int out_size, void* d_ws, size_t ws_size,
                              hipStream_t stream) {
  const float* x = (const float*)d_in[0];
  const int*   w = (const int*)d_in[1];
  const float* s = (const float*)d_in[2];
  float*     out = (float*)d_out;

  // d_ws: xb f16 [8192][4096] (64 MB) | wq packed u32 (21.5 MB) | st f16 (1.35 MB)
  unsigned short* xb = (unsigned short*)d_ws;
  unsigned char*  wq = (unsigned char*)d_ws + (size_t)M_ROWS * IN_F * 2;
  unsigned short* st = (unsigned short*)(wq + (size_t)OUT_F * (IN_F / 2));

  pack_w<<<dim3(2048), dim3(256), 0, stream>>>(w, (unsigned int*)wq);
  scale_t<<<dim3(43, 64), dim3(256), 0, stream>>>(s, st);
  cvt_x<<<dim3(2048), dim3(256), 0, stream>>>(x, xb);
  gemm_bt<<<dim3((M_ROWS / BM) * (OUT_F / BN)), dim3(512), 0, stream>>>(xb, wq, st, out);
}

// Round 16
// 737.911 us; speedup vs baseline: 1.1018x; 1.1018x over previous
//
#include <hip/hip_runtime.h>
#include <stdint.h>

// ===== LinearQ4_0: out[8192,11008] = x[8192,4096] * W^T, W q4_0 packed =====
#define IN_F   4096
#define OUT_F  11008
#define M_ROWS 8192
#define BM 256
#define BN 256
#define BK 64
#define NTILE_K (IN_F / BK)   // 64 K-tiles, 2 per iteration -> 32 iters

typedef __attribute__((ext_vector_type(4))) float  f32x4;
typedef __attribute__((ext_vector_type(4))) int    int4v;
typedef __attribute__((ext_vector_type(8))) unsigned short ushort8;
typedef __bf16 bf16x8 __attribute__((ext_vector_type(8)));

__device__ __forceinline__ unsigned short f2bf(float f) {
  unsigned int u = __builtin_bit_cast(unsigned int, f);
  u += 0x7fffu + ((u >> 16) & 1u);
  return (unsigned short)(u >> 16);
}

// ---- kernel 1: fused prep. Blocks [0,1024): dequant W -> bf16; [1024,2048): x -> bf16.
// Fusing saves one launch boundary and overlaps the two BW-bound streams' tails.
__global__ __launch_bounds__(256) void prep(const int* __restrict__ w,
                                            const float* __restrict__ sc,
                                            unsigned short* __restrict__ wb,
                                            const float* __restrict__ x,
                                            unsigned short* __restrict__ xb) {
  if (blockIdx.x < 1024) {
    const int total8 = (OUT_F * IN_F) / 8;
    for (int t = blockIdx.x * 256 + threadIdx.x; t < total8; t += 1024 * 256) {
      const int f0  = t * 8;
      const int p   = f0 >> 7;
      const int nib = (f0 >> 6) & 1;
      const int j0  = f0 & 63;
      const float scale = sc[f0 >> 6];
      const int* src = w + p * 64 + j0;
      const int4v b0 = __builtin_nontemporal_load(reinterpret_cast<const int4v*>(src));
      const int4v b1 = __builtin_nontemporal_load(reinterpret_cast<const int4v*>(src + 4));
      ushort8 r;
#pragma unroll
      for (int e = 0; e < 4; ++e) {
        const int v0 = b0[e], v1 = b1[e];
        const int q0 = nib ? ((v0 << 28) >> 28) : (v0 >> 4);
        const int q1 = nib ? ((v1 << 28) >> 28) : (v1 >> 4);
        r[e]     = f2bf((float)q0 * scale);
        r[4 + e] = f2bf((float)q1 * scale);
      }
      *reinterpret_cast<ushort8*>(wb + f0) = r;
    }
  } else {
    const int total8 = (M_ROWS * IN_F) / 8;
    for (int t = (blockIdx.x - 1024) * 256 + threadIdx.x; t < total8; t += 1024 * 256) {
      const f32x4 a0 = __builtin_nontemporal_load(reinterpret_cast<const f32x4*>(x + t * 8));
      const f32x4 a1 = __builtin_nontemporal_load(reinterpret_cast<const f32x4*>(x + t * 8 + 4));
      ushort8 r;
#pragma unroll
      for (int e = 0; e < 4; ++e) {
        r[e]     = f2bf(a0[e]);
        r[4 + e] = f2bf(a1[e]);
      }
      *reinterpret_cast<ushort8*>(xb + t * 8) = r;
    }
  }
}

// ---- async global -> LDS, 16 B per lane ----
__device__ __forceinline__ void gld16(const void* g, void* l) {
  __builtin_amdgcn_global_load_lds(
      (const __attribute__((address_space(1))) unsigned int*)(uintptr_t)g,
      (__attribute__((address_space(3))) unsigned int*)(unsigned int)(uintptr_t)l,
      16, 0, 0);
}

#define BAR() do { asm volatile("" ::: "memory"); __builtin_amdgcn_s_barrier(); \
                   asm volatile("" ::: "memory"); } while (0)

// ---- kernel 2: 8-phase, 1 barrier/phase, ONE-PHASE-AHEAD fragment reads. ----
// (Best-measured configuration: R9 bench, GEMM ~670 us, MfmaUtil ~54%.)
// Phase i = {STAGE (2 loads); RD(frags for MFMA i+1, alternate reg set);
//            [vmcnt(6) on odd phases]; BAR; MFMA(i) from current set}.
// Residency ledger (FIFO-sim; 2 loads/phase; vmcnt(6) at P1,P3,P5,P7):
//   prologue leaves [0A1,0B1,1A0,1B0] in flight (= P8-exit state).
//   P1-wait drains 0A1,0B1 (RD P2,P3)   P3-wait drains 1A0,1B0 (RD P4,P5)
//   P5-wait drains 1A1,1B1 (RD P6,P7)   P7-wait drains 0A0',0B0' (RD P8,P1')
// WAR: every stage target's last reader is a phase-top RD >=1 barrier earlier.
// LDS [buf][A|B][kh][256][32] 64B rows, swizzle chunk^=((row>>1)&3);
// linear gld dest + inverse-swizzled global source + same XOR on ds_read.
__global__ __launch_bounds__(512, 2) void gemm_bt(const unsigned short* __restrict__ A,
                                                  const unsigned short* __restrict__ B,
                                                  float* __restrict__ C) {
  __shared__ __align__(16) unsigned short lds[65536];  // 128 KB

  const int NT  = OUT_F / BN;              // 43
  const int nwg = (M_ROWS / BM) * NT;      // 1376, %8==0
  const int cpx = nwg >> 3;
  const int bid = blockIdx.x;
  const int swz = (bid & 7) * cpx + (bid >> 3);
  const int mt  = swz / NT;
  const int nt  = swz - mt * NT;

  const int tid  = threadIdx.x;
  const int lane = tid & 63;
  const int wid  = tid >> 6;      // 8 waves: 2 (M) x 4 (N)
  const int wr   = wid >> 2;      // 0..1 -> 128 rows
  const int wc   = wid & 3;       // 0..3 -> 64 cols

  // ---- staging: thread t -> row t>>2, phys chunk t&3; logical chunk = pc ^ ((row>>1)&3) ----
  const int r_st = tid >> 2;
  const int lc   = (tid & 3) ^ ((tid >> 3) & 3);
  const unsigned short* gA = A + (size_t)(mt * BM + r_st) * IN_F + lc * 8;
  const unsigned short* gB = B + (size_t)(nt * BM + r_st) * IN_F + lc * 8;
  unsigned short* ldsw = lds + tid * 8;   // linear dest within each 8KB sweep

  // region base (ushorts): buf*32768 + (B?16384:0) + kh*8192 ; sweep2 at +4096
#define STAGE_A(b, h, kk) do {                                              \
    unsigned short* d_ = ldsw + (b) * 32768 + (h) * 8192;                   \
    const unsigned short* s_ = gA + (kk) + (h) * 32;                        \
    gld16(s_, d_); gld16(s_ + (size_t)128 * IN_F, d_ + 4096);               \
  } while (0)
#define STAGE_B(b, h, kk) do {                                              \
    unsigned short* d_ = ldsw + (b) * 32768 + 16384 + (h) * 8192;           \
    const unsigned short* s_ = gB + (kk) + (h) * 32;                        \
    gld16(s_, d_); gld16(s_ + (size_t)128 * IN_F, d_ + 4096);               \
  } while (0)

  // ---- fragment reads: row (bits 0-3 = fr) -> chunk (kq ^ (fr>>1)&3) ----
  const int fr   = lane & 15;
  const int kq   = lane >> 4;
  const int coff = (kq ^ ((fr >> 1) & 3)) * 8;   // ushort offset within 32-col row

  bf16x8 aS0[4], aS1[4], bS0[4], bS1[4];
#define RD_A(dst, b, h, mq) do {                                            \
    const unsigned short* p_ = lds + (b) * 32768 + (h) * 8192 + coff;       \
    _Pragma("unroll") for (int mm = 0; mm < 4; ++mm)                        \
      dst[mm] = *reinterpret_cast<const bf16x8*>(                           \
          p_ + (size_t)(wr * 128 + (mq) * 64 + mm * 16 + fr) * 32);         \
  } while (0)
#define RD_B(dst, b, h) do {                                                \
    const unsigned short* p_ = lds + (b) * 32768 + 16384 + (h) * 8192 + coff; \
    _Pragma("unroll") for (int nn = 0; nn < 4; ++nn)                        \
      dst[nn] = *reinterpret_cast<const bf16x8*>(                           \
          p_ + (size_t)(wc * 64 + nn * 16 + fr) * 32);                      \
  } while (0)

  f32x4 acc[8][4] = {};
#define MFMA16(mq, aset, bset) do {                                         \
    __builtin_amdgcn_s_setprio(1);                                          \
    _Pragma("unroll") for (int mm = 0; mm < 4; ++mm)                        \
      _Pragma("unroll") for (int nn = 0; nn < 4; ++nn)                      \
        acc[(mq)*4+mm][nn] = __builtin_amdgcn_mfma_f32_16x16x32_bf16(       \
            aset[mm], bset[nn], acc[(mq)*4+mm][nn], 0, 0, 0);               \
    __builtin_amdgcn_s_setprio(0);                                          \
  } while (0)

#define VWAIT6() asm volatile("s_waitcnt vmcnt(6)" ::: "memory")

  // ---- prologue: 12 loads; vmcnt(8) -> 0kh0 resident; in-flight = P8-exit state;
  //      pre-read MFMA(P1)'s frags (0kh0 m0-3 + b) ----
  STAGE_A(0, 0, 0); STAGE_B(0, 0, 0);
  STAGE_A(0, 1, 0); STAGE_B(0, 1, 0);
  STAGE_A(1, 0, BK); STAGE_B(1, 0, BK);
  asm volatile("s_waitcnt vmcnt(8)" ::: "memory");
  BAR();
  RD_A(aS0, 0, 0, 0); RD_B(bS0, 0, 0);

  for (int it = 0; it < NTILE_K / 2; ++it) {
    const int kt1 = ((2 * it + 1) & (NTILE_K - 1)) * BK;   // cur Tb
    const int kt2 = ((2 * it + 2) & (NTILE_K - 1)) * BK;   // next Ta
    const int kt3 = ((2 * it + 3) & (NTILE_K - 1)) * BK;   // next Tb

    // P1: stage 1A1 ; RD->P2 (0kh0 m4-7) ; publish 0kh1 ; MFMA 0kh0 m0-3
    STAGE_A(1, 1, kt1); RD_A(aS1, 0, 0, 1); VWAIT6();
    BAR(); MFMA16(0, aS0, bS0);
    // P2: stage 1B1 ; RD->P3 (0kh1 m0-3 + b) ; MFMA 0kh0 m4-7
    STAGE_B(1, 1, kt1); RD_A(aS0, 0, 1, 0); RD_B(bS1, 0, 1);
    BAR(); MFMA16(1, aS1, bS0);
    // P3: stage next 0A0 ; RD->P4 (0kh1 m4-7) ; publish 1kh0 ; MFMA 0kh1 m0-3
    STAGE_A(0, 0, kt2); RD_A(aS1, 0, 1, 1); VWAIT6();
    BAR(); MFMA16(0, aS0, bS1);
    // P4: stage next 0B0 ; RD->P5 (1kh0 m0-3 + b) ; MFMA 0kh1 m4-7
    STAGE_B(0, 0, kt2); RD_A(aS0, 1, 0, 0); RD_B(bS0, 1, 0);
    BAR(); MFMA16(1, aS1, bS1);
    // P5: stage next 0A1 ; RD->P6 (1kh0 m4-7) ; publish 1kh1 ; MFMA 1kh0 m0-3
    STAGE_A(0, 1, kt2); RD_A(aS1, 1, 0, 1); VWAIT6();
    BAR(); MFMA16(0, aS0, bS0);
    // P6: stage next 0B1 ; RD->P7 (1kh1 m0-3 + b) ; MFMA 1kh0 m4-7
    STAGE_B(0, 1, kt2); RD_A(aS0, 1, 1, 0); RD_B(bS1, 1, 1);
    BAR(); MFMA16(1, aS1, bS0);
    // P7: stage next 1A0 ; RD->P8 (1kh1 m4-7) ; publish next 0kh0 ; MFMA 1kh1 m0-3
    STAGE_A(1, 0, kt3); RD_A(aS1, 1, 1, 1); VWAIT6();
    BAR(); MFMA16(0, aS0, bS1);
    // P8: stage next 1B0 ; RD->next P1 (next-Ta 0kh0 m0-3 + b) ; MFMA 1kh1 m4-7
    STAGE_B(1, 0, kt3); RD_A(aS0, 0, 0, 0); RD_B(bS0, 0, 0);
    BAR(); MFMA16(1, aS1, bS1);
  }

  // ---- epilogue: plain stores (nt-store regressed WRITE_SIZE 27% in R6) ----
  const int col  = nt * BN + wc * 64 + fr;
  const int row0 = mt * BM + wr * 128 + (lane >> 4) * 4;
#pragma unroll
  for (int m = 0; m < 8; ++m) {
#pragma unroll
    for (int n = 0; n < 4; ++n) {
      float* cp = C + (size_t)(row0 + m * 16) * OUT_F + (col + n * 16);
#pragma unroll
      for (int r = 0; r < 4; ++r) cp[(size_t)r * OUT_F] = acc[m][n][r];
    }
  }
}

extern "C" void kernel_launch(void* const* d_in, const int* in_sizes, int n_in,
                              void* d_out, int out_size, void* d_ws, size_t ws_size,
                              hipStream_t stream) {
  const float* x = (const float*)d_in[0];
  const int*   w = (const int*)d_in[1];
  const float* s = (const float*)d_in[2];
  float*     out = (float*)d_out;

  unsigned short* wb = (unsigned short*)d_ws;             // bf16 W  [OUT_F][IN_F]
  unsigned short* xb = wb + (size_t)OUT_F * IN_F;         // bf16 x  [M_ROWS][IN_F]

  prep<<<dim3(2048), dim3(256), 0, stream>>>(w, s, wb, x, xb);
  gemm_bt<<<dim3((M_ROWS / BM) * (OUT_F / BN)), dim3(512), 0, stream>>>(xb, wb, out);
}